// Round 7
// baseline (14264.227 us; speedup 1.0000x reference)
//
#include <hip/hip_runtime.h>
#include <hip/hip_bf16.h>

#define N_NODES 10000
#define N_EDGES 100000
#define DEPTH   6
#define E_CHUNK 12500   // prep-only chunking (h1 staging)

typedef __attribute__((ext_vector_type(8))) short short8;
typedef __attribute__((ext_vector_type(4))) float f32x4;
typedef unsigned short u16;

__device__ __forceinline__ float bf2f(u16 u) {
    union { float f; unsigned int i; } v; v.i = ((unsigned int)u) << 16; return v.f;
}
__device__ __forceinline__ u16 f2bf(float f) {
    union { float f; unsigned int i; } v; v.f = f;
    unsigned int x = v.i;
    unsigned int r = (x + 0x7fffu + ((x >> 16) & 1u)) >> 16;
    return (u16)r;
}

// async global->LDS, 16B per lane
__device__ __forceinline__ void gload_lds16(const void* g, void* s) {
    __builtin_amdgcn_global_load_lds((const __attribute__((address_space(1))) void*)g,
                                     (__attribute__((address_space(3))) void*)s, 16, 0, 0);
}

// ---------------- one-time weight prep ----------------
__global__ void k2_transpose_kernel(const float* __restrict__ k2w, u16* __restrict__ k2T) {
    int idx = blockIdx.x * 256 + threadIdx.x;  // 1024*1024
    int n = idx >> 10, k = idx & 1023;
    k2T[idx] = f2bf(k2w[k * 1024 + n]);
}
// GEMM3 column n = o*64+i takes k3w column i*64+o (o-major: n-tile = 2 o's x 64 i)
__global__ void k3_permT_kernel(const float* __restrict__ k3w, u16* __restrict__ k3pT) {
    int idx = blockIdx.x * 256 + threadIdx.x;  // 4096*1024
    int n = idx >> 10, c = idx & 1023;
    k3pT[idx] = f2bf(k3w[(size_t)c * 4096 + (n & 63) * 64 + (n >> 6)]);
}
__global__ void b3_permute_kernel(const float* __restrict__ b3, float* __restrict__ b3p) {
    int n = blockIdx.x * 256 + threadIdx.x;  // 4096
    if (n >= 4096) return;
    b3p[n] = b3[(n & 63) * 64 + (n >> 6)];
}

// ---------------- degree ----------------
__global__ void deg_kernel(const int* __restrict__ ei, float* __restrict__ deg) {
    int e = blockIdx.x * 256 + threadIdx.x;
    if (e < N_EDGES) atomicAdd(&deg[ei[N_EDGES + e]], 1.0f);
}

// ---------------- layer 1 (per chunk): h1 = relu(ea @ k1 + b1), bf16 ----------------
__global__ void gemm1_kernel(const float* __restrict__ ea, const float* __restrict__ k1w,
                             const float* __restrict__ k1b, u16* __restrict__ h1, int e0) {
    int idx = blockIdx.x * 256 + threadIdx.x;  // E_CHUNK*1024
    int c = idx & 1023;
    int e = (idx >> 10) + e0;
    float acc = k1b[c];
#pragma unroll
    for (int i = 0; i < 6; i++) acc += ea[e * 6 + i] * k1w[i * 1024 + c];
    h1[idx] = f2bf(fmaxf(acc, 0.0f));
}

// ---------------- prep GEMM (h2 build): 128x128 tile, bf16 out ----------------
template <int NOUT, bool RELU>
__global__ __launch_bounds__(256) void gemm128_kernel(const u16* __restrict__ A,
                                                      const u16* __restrict__ BT,
                                                      const float* __restrict__ bias,
                                                      u16* __restrict__ C, int M) {
    constexpr int K = 1024;
    __shared__ __align__(16) u16 Alds[128 * 32];
    __shared__ __align__(16) u16 Blds[128 * 32];

    const int t = threadIdx.x;
    const int lane = t & 63, w = t >> 6;
    const int wm = w >> 1, wn = w & 1;
    const int fm = lane & 15, q = lane >> 4;
    const int m0 = blockIdx.y * 128;
    const int n0 = blockIdx.x * 128;

    f32x4 acc[4][4];
#pragma unroll
    for (int a = 0; a < 4; a++)
#pragma unroll
        for (int b = 0; b < 4; b++) acc[a][b] = (f32x4){0.f, 0.f, 0.f, 0.f};

    int ar0 = m0 + (t >> 2);        if (ar0 >= M) ar0 = M - 1;
    int ar1 = m0 + 64 + (t >> 2);   if (ar1 >= M) ar1 = M - 1;
    const u16* gA0 = A + (size_t)ar0 * K + (t & 3) * 8;
    const u16* gA1 = A + (size_t)ar1 * K + (t & 3) * 8;
    const u16* gB0 = BT + (size_t)(n0 + (t >> 2)) * K + (t & 3) * 8;
    const u16* gB1 = BT + (size_t)(n0 + 64 + (t >> 2)) * K + (t & 3) * 8;
    u16* lA0 = &Alds[t * 8];
    u16* lA1 = &Alds[2048 + t * 8];
    u16* lB0 = &Blds[t * 8];
    u16* lB1 = &Blds[2048 + t * 8];

    for (int k0 = 0; k0 < K; k0 += 32) {
        gload_lds16(gA0 + k0, lA0);
        gload_lds16(gA1 + k0, lA1);
        gload_lds16(gB0 + k0, lB0);
        gload_lds16(gB1 + k0, lB1);
        __syncthreads();
        short8 af[4], bf[4];
#pragma unroll
        for (int mi = 0; mi < 4; mi++)
            af[mi] = *reinterpret_cast<const short8*>(&Alds[(wm * 64 + mi * 16 + fm) * 32 + q * 8]);
#pragma unroll
        for (int ni = 0; ni < 4; ni++)
            bf[ni] = *reinterpret_cast<const short8*>(&Blds[(wn * 64 + ni * 16 + fm) * 32 + q * 8]);
#pragma unroll
        for (int mi = 0; mi < 4; mi++)
#pragma unroll
            for (int ni = 0; ni < 4; ni++)
                acc[mi][ni] = __builtin_amdgcn_mfma_f32_16x16x32_bf16(af[mi], bf[ni], acc[mi][ni], 0, 0, 0);
        __syncthreads();
    }

#pragma unroll
    for (int mi = 0; mi < 4; mi++) {
#pragma unroll
        for (int ni = 0; ni < 4; ni++) {
            int col = n0 + wn * 64 + ni * 16 + fm;
            float bsv = bias[col];
#pragma unroll
            for (int r = 0; r < 4; r++) {
                int row = m0 + wm * 64 + mi * 16 + q * 4 + r;
                if (row < M) {
                    float v = acc[mi][ni][r] + bsv;
                    if (RELU) v = fmaxf(v, 0.0f);
                    C[(size_t)row * NOUT + col] = f2bf(v);
                }
            }
        }
    }
}

// ---------------- fused GEMM3+msg: A via LDS, B DIRECT FROM GLOBAL ----------------
// K-loop was LDS-read-pipe-bound (32 ds_read_b128/iter/CU = 384 cyc vs 307 MFMA).
// B (k3pT, 8.4 MB, L2/L3-resident) fragments load straight to registers:
// BT[(n0+wn*64+ni*16+fm)*1024 + k0 + q*8], 16B/lane. Halves LDS reads + staging.
// Epilogue (round-5 verified): col = o*64+i; per (mi,r): partial = sum_ni
// (acc+bias)*z[src,i], shfl-reduce over 16 fm lanes, fm==0 atomicAdd agg[dst,o].
__global__ __launch_bounds__(256) void gemm_msg_kernel(
    const u16* __restrict__ A, const u16* __restrict__ BT,
    const float* __restrict__ bias, const int* __restrict__ ei,
    const float* __restrict__ z, float* __restrict__ agg, int M) {
    constexpr int K = 1024;
    __shared__ __align__(16) u16 Alds[128 * 32];   // 8 KB only

    const int t = threadIdx.x;
    const int lane = t & 63, w = t >> 6;
    const int wm = w >> 1, wn = w & 1;
    const int fm = lane & 15, q = lane >> 4;
    const int m0 = blockIdx.y * 128;
    const int n0 = blockIdx.x * 128;

    f32x4 acc[4][4];
#pragma unroll
    for (int a = 0; a < 4; a++)
#pragma unroll
        for (int b = 0; b < 4; b++) acc[a][b] = (f32x4){0.f, 0.f, 0.f, 0.f};

    int ar0 = m0 + (t >> 2);        if (ar0 >= M) ar0 = M - 1;
    int ar1 = m0 + 64 + (t >> 2);   if (ar1 >= M) ar1 = M - 1;
    const u16* gA0 = A + (size_t)ar0 * K + (t & 3) * 8;
    const u16* gA1 = A + (size_t)ar1 * K + (t & 3) * 8;
    u16* lA0 = &Alds[t * 8];
    u16* lA1 = &Alds[2048 + t * 8];

    const u16* gBf[4];
#pragma unroll
    for (int ni = 0; ni < 4; ni++)
        gBf[ni] = BT + (size_t)(n0 + wn * 64 + ni * 16 + fm) * K + q * 8;

    for (int k0 = 0; k0 < K; k0 += 32) {
        gload_lds16(gA0 + k0, lA0);
        gload_lds16(gA1 + k0, lA1);
        short8 bf[4];
#pragma unroll
        for (int ni = 0; ni < 4; ni++)
            bf[ni] = *reinterpret_cast<const short8*>(gBf[ni] + k0);
        __syncthreads();
        short8 af[4];
#pragma unroll
        for (int mi = 0; mi < 4; mi++)
            af[mi] = *reinterpret_cast<const short8*>(&Alds[(wm * 64 + mi * 16 + fm) * 32 + q * 8]);
#pragma unroll
        for (int mi = 0; mi < 4; mi++)
#pragma unroll
            for (int ni = 0; ni < 4; ni++)
                acc[mi][ni] = __builtin_amdgcn_mfma_f32_16x16x32_bf16(af[mi], bf[ni], acc[mi][ni], 0, 0, 0);
        __syncthreads();
    }

    // epilogue: o = (n0>>6)+wn (uniform/wave); i = ni*16+fm
    const int o = (n0 >> 6) + wn;
    float bsv[4];
    int iidx[4];
#pragma unroll
    for (int ni = 0; ni < 4; ni++) {
        bsv[ni] = bias[n0 + wn * 64 + ni * 16 + fm];
        iidx[ni] = ni * 16 + fm;
    }
#pragma unroll
    for (int mi = 0; mi < 4; mi++) {
#pragma unroll
        for (int r = 0; r < 4; r++) {
            int e = m0 + wm * 64 + mi * 16 + q * 4 + r;  // uniform across fm-group
            float partial = 0.f;
            int dst = 0;
            if (e < M) {
                int src = ei[e];
                dst = ei[N_EDGES + e];
                const float* zs = z + (size_t)src * 64;
#pragma unroll
                for (int ni = 0; ni < 4; ni++)
                    partial += (acc[mi][ni][r] + bsv[ni]) * zs[iidx[ni]];
            }
            partial += __shfl_xor(partial, 1);
            partial += __shfl_xor(partial, 2);
            partial += __shfl_xor(partial, 4);
            partial += __shfl_xor(partial, 8);
            if (fm == 0 && e < M) atomicAdd(&agg[(size_t)dst * 64 + o], partial);
        }
    }
}

// ---------------- z0 = x @ fc1_w + fc1_b ----------------
__global__ void z0_kernel(const float* __restrict__ x, const float* __restrict__ w,
                          const float* __restrict__ b, float* __restrict__ z) {
    int idx = blockIdx.x * 256 + threadIdx.x;  // N*64
    int n = idx >> 6, o = idx & 63;
    z[idx] = x[n] * w[o] + b[o];
}

// ---------------- z_new = relu(agg/deg + z @ root_w + conv_b) ----------------
__global__ __launch_bounds__(256) void update_kernel(const float* __restrict__ zin,
                                                     const float* __restrict__ agg,
                                                     const float* __restrict__ deg,
                                                     const float* __restrict__ rootw,
                                                     const float* __restrict__ convb,
                                                     float* __restrict__ zout) {
    int n = blockIdx.x * 4 + (threadIdx.x >> 6);
    int o = threadIdx.x & 63;
    float r = convb[o];
    const float* zr = zin + (size_t)n * 64;
#pragma unroll 8
    for (int i = 0; i < 64; i++) r += zr[i] * rootw[i * 64 + o];
    float d = deg[n];
    d = d < 1.0f ? 1.0f : d;
    float v = agg[(size_t)n * 64 + o] / d + r;
    zout[(size_t)n * 64 + o] = fmaxf(v, 0.0f);
}

// ---------------- out = z @ fc2_w + fc2_b ----------------
__global__ void final_kernel(const float* __restrict__ z, const float* __restrict__ w,
                             const float* __restrict__ b, float* __restrict__ out) {
    int n = blockIdx.x * 256 + threadIdx.x;
    if (n >= N_NODES) return;
    float acc = b[0];
#pragma unroll 8
    for (int o = 0; o < 64; o++) acc += z[(size_t)n * 64 + o] * w[o];
    out[n] = acc;
}

// ---------------- diagnostic ----------------
__global__ void dbg_kernel(float* __restrict__ out, float val, int n) {
    int i = blockIdx.x * 256 + threadIdx.x;
    if (i < n) out[i] = val;
}

extern "C" void kernel_launch(void* const* d_in, const int* in_sizes, int n_in,
                              void* d_out, int out_size, void* d_ws, size_t ws_size,
                              hipStream_t stream) {
    const float* x     = (const float*)d_in[0];
    const int*   ei    = (const int*)  d_in[1];
    const float* ea    = (const float*)d_in[2];
    const float* fc1w  = (const float*)d_in[3];
    const float* fc1b  = (const float*)d_in[4];
    const float* k1w   = (const float*)d_in[5];
    const float* k1b   = (const float*)d_in[6];
    const float* k2w   = (const float*)d_in[7];
    const float* k2b   = (const float*)d_in[8];
    const float* k3w   = (const float*)d_in[9];
    const float* k3b   = (const float*)d_in[10];
    const float* rootw = (const float*)d_in[11];
    const float* convb = (const float*)d_in[12];
    const float* fc2w  = (const float*)d_in[13];
    const float* fc2b  = (const float*)d_in[14];
    float* out = (float*)d_out;

    // h2 204.8 + h1ch 25.6 + k2T 2.1 + k3pT 8.4 + b3p + zA/zB/agg 7.7 + deg 0.04
    // = 248.7 MB < 268.4 MB (ws = 256 MiB)
    const size_t NEED = 249000000;
    if (ws_size < NEED) {
        dbg_kernel<<<(N_NODES + 255) / 256, 256, 0, stream>>>(out, (float)(ws_size >> 20), N_NODES);
        return;
    }

    char* p = (char*)d_ws;
    auto alloc = [&](size_t bytes) {
        char* r = p;
        p += (bytes + 255) & ~(size_t)255;
        return r;
    };
    u16*   h2   = (u16*)  alloc((size_t)N_EDGES * 1024 * 2);   // 204.8 MB
    u16*   h1ch = (u16*)  alloc((size_t)E_CHUNK * 1024 * 2);   // 25.6 MB (prep only)
    u16*   k2T  = (u16*)  alloc((size_t)1024 * 1024 * 2);
    u16*   k3pT = (u16*)  alloc((size_t)4096 * 1024 * 2);
    float* b3p  = (float*)alloc(4096 * 4);
    float* zA   = (float*)alloc((size_t)N_NODES * 64 * 4);
    float* zB   = (float*)alloc((size_t)N_NODES * 64 * 4);
    float* agg  = (float*)alloc((size_t)N_NODES * 64 * 4);
    float* deg  = (float*)alloc((size_t)N_NODES * 4);

    hipMemsetAsync(deg, 0, (size_t)N_NODES * 4, stream);

    k2_transpose_kernel<<<(1024 * 1024) / 256, 256, 0, stream>>>(k2w, k2T);
    k3_permT_kernel<<<(4096 * 1024) / 256, 256, 0, stream>>>(k3w, k3pT);
    b3_permute_kernel<<<16, 256, 0, stream>>>(k3b, b3p);
    deg_kernel<<<(N_EDGES + 255) / 256, 256, 0, stream>>>(ei, deg);

    // h2 = relu(relu(ea@k1+b1)@k2+b2), bf16, once (edge_attr depth-invariant)
    for (int e0 = 0; e0 < N_EDGES; e0 += E_CHUNK) {
        gemm1_kernel<<<(E_CHUNK * 1024) / 256, 256, 0, stream>>>(ea, k1w, k1b, h1ch, e0);
        dim3 g2(1024 / 128, (E_CHUNK + 127) / 128);
        gemm128_kernel<1024, true><<<g2, 256, 0, stream>>>(
            h1ch, k2T, k2b, h2 + (size_t)e0 * 1024, E_CHUNK);
    }

    z0_kernel<<<(N_NODES * 64) / 256, 256, 0, stream>>>(x, fc1w, fc1b, zA);

    float* zin = zA;
    float* zout = zB;
    for (int d = 0; d < DEPTH; d++) {
        hipMemsetAsync(agg, 0, (size_t)N_NODES * 64 * 4, stream);
        dim3 g3(4096 / 128, (N_EDGES + 127) / 128);  // 32 n-tiles x 782 m-tiles
        gemm_msg_kernel<<<g3, 256, 0, stream>>>(h2, k3pT, b3p, ei, zin, agg, N_EDGES);
        update_kernel<<<N_NODES / 4, 256, 0, stream>>>(zin, agg, deg, rootw, convb, zout);
        float* tmp = zin; zin = zout; zout = tmp;
    }

    final_kernel<<<(N_NODES + 255) / 256, 256, 0, stream>>>(zin, fc2w, fc2b, out);
}

// Round 8
// 7678.981 us; speedup vs baseline: 1.8576x; 1.8576x over previous
//
#include <hip/hip_runtime.h>
#include <hip/hip_bf16.h>

#define N_NODES 10000
#define N_EDGES 100000
#define DEPTH   6
#define E_CHUNK 12500   // prep-only chunking (h1 staging)

typedef __attribute__((ext_vector_type(8))) short short8;
typedef __attribute__((ext_vector_type(4))) float f32x4;
typedef unsigned short u16;

__device__ __forceinline__ float bf2f(u16 u) {
    union { float f; unsigned int i; } v; v.i = ((unsigned int)u) << 16; return v.f;
}
__device__ __forceinline__ u16 f2bf(float f) {
    union { float f; unsigned int i; } v; v.f = f;
    unsigned int x = v.i;
    unsigned int r = (x + 0x7fffu + ((x >> 16) & 1u)) >> 16;
    return (u16)r;
}

// async global->LDS, 16B per lane
__device__ __forceinline__ void gload_lds16(const void* g, void* s) {
    __builtin_amdgcn_global_load_lds((const __attribute__((address_space(1))) void*)g,
                                     (__attribute__((address_space(3))) void*)s, 16, 0, 0);
}

// ---------------- one-time weight prep ----------------
__global__ void k2_transpose_kernel(const float* __restrict__ k2w, u16* __restrict__ k2T) {
    int idx = blockIdx.x * 256 + threadIdx.x;  // 1024*1024
    int n = idx >> 10, k = idx & 1023;
    k2T[idx] = f2bf(k2w[k * 1024 + n]);
}
// o-major permuted transpose: col n=(o,i) takes k3w column i*64+o
__global__ void k3_permT_kernel(const float* __restrict__ k3w, u16* __restrict__ k3pT) {
    int idx = blockIdx.x * 256 + threadIdx.x;  // 4096*1024
    int n = idx >> 10, c = idx & 1023;
    k3pT[idx] = f2bf(k3w[(size_t)c * 4096 + (n & 63) * 64 + (n >> 6)]);
}
__global__ void b3_permute_kernel(const float* __restrict__ b3, float* __restrict__ b3p) {
    int n = blockIdx.x * 256 + threadIdx.x;  // 4096
    if (n >= 4096) return;
    b3p[n] = b3[(n & 63) * 64 + (n >> 6)];
}

// ---------------- degree ----------------
__global__ void deg_kernel(const int* __restrict__ ei, float* __restrict__ deg) {
    int e = blockIdx.x * 256 + threadIdx.x;
    if (e < N_EDGES) atomicAdd(&deg[ei[N_EDGES + e]], 1.0f);
}

// ---------------- layer 1 (per chunk): h1 = relu(ea @ k1 + b1), bf16 ----------------
__global__ void gemm1_kernel(const float* __restrict__ ea, const float* __restrict__ k1w,
                             const float* __restrict__ k1b, u16* __restrict__ h1, int e0) {
    int idx = blockIdx.x * 256 + threadIdx.x;  // E_CHUNK*1024
    int c = idx & 1023;
    int e = (idx >> 10) + e0;
    float acc = k1b[c];
#pragma unroll
    for (int i = 0; i < 6; i++) acc += ea[e * 6 + i] * k1w[i * 1024 + c];
    h1[idx] = f2bf(fmaxf(acc, 0.0f));
}

// ---------------- prep GEMM (h2 build): 128x128 tile, bf16 out ----------------
template <int NOUT, bool RELU>
__global__ __launch_bounds__(256) void gemm128_kernel(const u16* __restrict__ A,
                                                      const u16* __restrict__ BT,
                                                      const float* __restrict__ bias,
                                                      u16* __restrict__ C, int M) {
    constexpr int K = 1024;
    __shared__ __align__(16) u16 Alds[128 * 32];
    __shared__ __align__(16) u16 Blds[128 * 32];

    const int t = threadIdx.x;
    const int lane = t & 63, w = t >> 6;
    const int wm = w >> 1, wn = w & 1;
    const int fm = lane & 15, q = lane >> 4;
    const int m0 = blockIdx.y * 128;
    const int n0 = blockIdx.x * 128;

    f32x4 acc[4][4];
#pragma unroll
    for (int a = 0; a < 4; a++)
#pragma unroll
        for (int b = 0; b < 4; b++) acc[a][b] = (f32x4){0.f, 0.f, 0.f, 0.f};

    int ar0 = m0 + (t >> 2);        if (ar0 >= M) ar0 = M - 1;
    int ar1 = m0 + 64 + (t >> 2);   if (ar1 >= M) ar1 = M - 1;
    const u16* gA0 = A + (size_t)ar0 * K + (t & 3) * 8;
    const u16* gA1 = A + (size_t)ar1 * K + (t & 3) * 8;
    const u16* gB0 = BT + (size_t)(n0 + (t >> 2)) * K + (t & 3) * 8;
    const u16* gB1 = BT + (size_t)(n0 + 64 + (t >> 2)) * K + (t & 3) * 8;
    u16* lA0 = &Alds[t * 8];
    u16* lA1 = &Alds[2048 + t * 8];
    u16* lB0 = &Blds[t * 8];
    u16* lB1 = &Blds[2048 + t * 8];

    for (int k0 = 0; k0 < K; k0 += 32) {
        gload_lds16(gA0 + k0, lA0);
        gload_lds16(gA1 + k0, lA1);
        gload_lds16(gB0 + k0, lB0);
        gload_lds16(gB1 + k0, lB1);
        __syncthreads();
        short8 af[4], bf[4];
#pragma unroll
        for (int mi = 0; mi < 4; mi++)
            af[mi] = *reinterpret_cast<const short8*>(&Alds[(wm * 64 + mi * 16 + fm) * 32 + q * 8]);
#pragma unroll
        for (int ni = 0; ni < 4; ni++)
            bf[ni] = *reinterpret_cast<const short8*>(&Blds[(wn * 64 + ni * 16 + fm) * 32 + q * 8]);
#pragma unroll
        for (int mi = 0; mi < 4; mi++)
#pragma unroll
            for (int ni = 0; ni < 4; ni++)
                acc[mi][ni] = __builtin_amdgcn_mfma_f32_16x16x32_bf16(af[mi], bf[ni], acc[mi][ni], 0, 0, 0);
        __syncthreads();
    }

#pragma unroll
    for (int mi = 0; mi < 4; mi++) {
#pragma unroll
        for (int ni = 0; ni < 4; ni++) {
            int col = n0 + wn * 64 + ni * 16 + fm;
            float bsv = bias[col];
#pragma unroll
            for (int r = 0; r < 4; r++) {
                int row = m0 + wm * 64 + mi * 16 + q * 4 + r;
                if (row < M) {
                    float v = acc[mi][ni][r] + bsv;
                    if (RELU) v = fmaxf(v, 0.0f);
                    C[(size_t)row * NOUT + col] = f2bf(v);
                }
            }
        }
    }
}

// ---------------- fused GEMM3+msg: 64x128 wave tile (mi=4, ni=8), block 128x256 ----
// FLOP/LDS-byte 42.7 vs 32 for 64x64 tile; epilogue+atomics per output halved.
// Both A and B staged via global_load_lds (round-7 showed direct-global B exposes
// L2 latency through the shared-vmcnt barrier drain).
// Epilogue: col = o*64+i (o-major); wave covers 2 o values (ni<4 and ni>=4);
// per (mi,r): two partials, two 4-step shfl trees over fm, fm==0 atomicAdds.
__global__ __launch_bounds__(256, 2) void gemm_msg_kernel(
    const u16* __restrict__ A, const u16* __restrict__ BT,
    const float* __restrict__ bias, const int* __restrict__ ei,
    const float* __restrict__ z, float* __restrict__ agg, int M) {
    constexpr int K = 1024;
    __shared__ __align__(16) u16 Alds[128 * 32];   // 8 KB
    __shared__ __align__(16) u16 Blds[256 * 32];   // 16 KB

    const int t = threadIdx.x;
    const int lane = t & 63, w = t >> 6;
    const int wm = w >> 1, wn = w & 1;
    const int fm = lane & 15, q = lane >> 4;
    const int m0 = blockIdx.y * 128;
    const int n0 = blockIdx.x * 256;

    f32x4 acc[4][8];
#pragma unroll
    for (int a = 0; a < 4; a++)
#pragma unroll
        for (int b = 0; b < 8; b++) acc[a][b] = (f32x4){0.f, 0.f, 0.f, 0.f};

    int ar0 = m0 + (t >> 2);        if (ar0 >= M) ar0 = M - 1;
    int ar1 = m0 + 64 + (t >> 2);   if (ar1 >= M) ar1 = M - 1;
    const u16* gA0 = A + (size_t)ar0 * K + (t & 3) * 8;
    const u16* gA1 = A + (size_t)ar1 * K + (t & 3) * 8;
    const u16* gB0 = BT + (size_t)(n0 + (t >> 2)) * K + (t & 3) * 8;
    const u16* gB1 = BT + (size_t)(n0 + 64 + (t >> 2)) * K + (t & 3) * 8;
    const u16* gB2 = BT + (size_t)(n0 + 128 + (t >> 2)) * K + (t & 3) * 8;
    const u16* gB3 = BT + (size_t)(n0 + 192 + (t >> 2)) * K + (t & 3) * 8;
    u16* lA0 = &Alds[t * 8];
    u16* lA1 = &Alds[2048 + t * 8];
    u16* lB0 = &Blds[t * 8];
    u16* lB1 = &Blds[2048 + t * 8];
    u16* lB2 = &Blds[4096 + t * 8];
    u16* lB3 = &Blds[6144 + t * 8];

    for (int k0 = 0; k0 < K; k0 += 32) {
        gload_lds16(gA0 + k0, lA0);
        gload_lds16(gA1 + k0, lA1);
        gload_lds16(gB0 + k0, lB0);
        gload_lds16(gB1 + k0, lB1);
        gload_lds16(gB2 + k0, lB2);
        gload_lds16(gB3 + k0, lB3);
        __syncthreads();
        short8 af[4], bf[8];
#pragma unroll
        for (int mi = 0; mi < 4; mi++)
            af[mi] = *reinterpret_cast<const short8*>(&Alds[(wm * 64 + mi * 16 + fm) * 32 + q * 8]);
#pragma unroll
        for (int ni = 0; ni < 8; ni++)
            bf[ni] = *reinterpret_cast<const short8*>(&Blds[(wn * 128 + ni * 16 + fm) * 32 + q * 8]);
#pragma unroll
        for (int mi = 0; mi < 4; mi++)
#pragma unroll
            for (int ni = 0; ni < 8; ni++)
                acc[mi][ni] = __builtin_amdgcn_mfma_f32_16x16x32_bf16(af[mi], bf[ni], acc[mi][ni], 0, 0, 0);
        __syncthreads();
    }

    // epilogue: o0 = blockIdx.x*4 + wn*2 (ni<4), o0+1 (ni>=4); i = (ni&3)*16+fm
    const int o0 = blockIdx.x * 4 + wn * 2;
    float bsv[8];
#pragma unroll
    for (int ni = 0; ni < 8; ni++)
        bsv[ni] = bias[n0 + wn * 128 + ni * 16 + fm];
#pragma unroll
    for (int mi = 0; mi < 4; mi++) {
#pragma unroll
        for (int r = 0; r < 4; r++) {
            int e = m0 + wm * 64 + mi * 16 + q * 4 + r;  // uniform across fm-group
            float p0 = 0.f, p1 = 0.f;
            int dst = 0;
            if (e < M) {
                int src = ei[e];
                dst = ei[N_EDGES + e];
                const float* zs = z + (size_t)src * 64;
                float zv[4];
#pragma unroll
                for (int j = 0; j < 4; j++) zv[j] = zs[j * 16 + fm];
#pragma unroll
                for (int ni = 0; ni < 4; ni++) {
                    p0 += (acc[mi][ni][r] + bsv[ni]) * zv[ni];
                    p1 += (acc[mi][ni + 4][r] + bsv[ni + 4]) * zv[ni];
                }
            }
            p0 += __shfl_xor(p0, 1);  p1 += __shfl_xor(p1, 1);
            p0 += __shfl_xor(p0, 2);  p1 += __shfl_xor(p1, 2);
            p0 += __shfl_xor(p0, 4);  p1 += __shfl_xor(p1, 4);
            p0 += __shfl_xor(p0, 8);  p1 += __shfl_xor(p1, 8);
            if (fm == 0 && e < M) {
                atomicAdd(&agg[(size_t)dst * 64 + o0], p0);
                atomicAdd(&agg[(size_t)dst * 64 + o0 + 1], p1);
            }
        }
    }
}

// ---------------- z0 = x @ fc1_w + fc1_b ----------------
__global__ void z0_kernel(const float* __restrict__ x, const float* __restrict__ w,
                          const float* __restrict__ b, float* __restrict__ z) {
    int idx = blockIdx.x * 256 + threadIdx.x;  // N*64
    int n = idx >> 6, o = idx & 63;
    z[idx] = x[n] * w[o] + b[o];
}

// ---------------- z_new = relu(agg/deg + z @ root_w + conv_b) ----------------
__global__ __launch_bounds__(256) void update_kernel(const float* __restrict__ zin,
                                                     const float* __restrict__ agg,
                                                     const float* __restrict__ deg,
                                                     const float* __restrict__ rootw,
                                                     const float* __restrict__ convb,
                                                     float* __restrict__ zout) {
    int n = blockIdx.x * 4 + (threadIdx.x >> 6);
    int o = threadIdx.x & 63;
    float r = convb[o];
    const float* zr = zin + (size_t)n * 64;
#pragma unroll 8
    for (int i = 0; i < 64; i++) r += zr[i] * rootw[i * 64 + o];
    float d = deg[n];
    d = d < 1.0f ? 1.0f : d;
    float v = agg[(size_t)n * 64 + o] / d + r;
    zout[(size_t)n * 64 + o] = fmaxf(v, 0.0f);
}

// ---------------- out = z @ fc2_w + fc2_b ----------------
__global__ void final_kernel(const float* __restrict__ z, const float* __restrict__ w,
                             const float* __restrict__ b, float* __restrict__ out) {
    int n = blockIdx.x * 256 + threadIdx.x;
    if (n >= N_NODES) return;
    float acc = b[0];
#pragma unroll 8
    for (int o = 0; o < 64; o++) acc += z[(size_t)n * 64 + o] * w[o];
    out[n] = acc;
}

// ---------------- diagnostic ----------------
__global__ void dbg_kernel(float* __restrict__ out, float val, int n) {
    int i = blockIdx.x * 256 + threadIdx.x;
    if (i < n) out[i] = val;
}

extern "C" void kernel_launch(void* const* d_in, const int* in_sizes, int n_in,
                              void* d_out, int out_size, void* d_ws, size_t ws_size,
                              hipStream_t stream) {
    const float* x     = (const float*)d_in[0];
    const int*   ei    = (const int*)  d_in[1];
    const float* ea    = (const float*)d_in[2];
    const float* fc1w  = (const float*)d_in[3];
    const float* fc1b  = (const float*)d_in[4];
    const float* k1w   = (const float*)d_in[5];
    const float* k1b   = (const float*)d_in[6];
    const float* k2w   = (const float*)d_in[7];
    const float* k2b   = (const float*)d_in[8];
    const float* k3w   = (const float*)d_in[9];
    const float* k3b   = (const float*)d_in[10];
    const float* rootw = (const float*)d_in[11];
    const float* convb = (const float*)d_in[12];
    const float* fc2w  = (const float*)d_in[13];
    const float* fc2b  = (const float*)d_in[14];
    float* out = (float*)d_out;

    // h2 204.8 + h1ch 25.6 + k2T 2.1 + k3pT 8.4 + b3p + zA/zB/agg 7.7 + deg 0.04
    // = 248.7 MB < 268.4 MB (ws = 256 MiB)
    const size_t NEED = 249000000;
    if (ws_size < NEED) {
        dbg_kernel<<<(N_NODES + 255) / 256, 256, 0, stream>>>(out, (float)(ws_size >> 20), N_NODES);
        return;
    }

    char* p = (char*)d_ws;
    auto alloc = [&](size_t bytes) {
        char* r = p;
        p += (bytes + 255) & ~(size_t)255;
        return r;
    };
    u16*   h2   = (u16*)  alloc((size_t)N_EDGES * 1024 * 2);   // 204.8 MB
    u16*   h1ch = (u16*)  alloc((size_t)E_CHUNK * 1024 * 2);   // 25.6 MB (prep only)
    u16*   k2T  = (u16*)  alloc((size_t)1024 * 1024 * 2);
    u16*   k3pT = (u16*)  alloc((size_t)4096 * 1024 * 2);
    float* b3p  = (float*)alloc(4096 * 4);
    float* zA   = (float*)alloc((size_t)N_NODES * 64 * 4);
    float* zB   = (float*)alloc((size_t)N_NODES * 64 * 4);
    float* agg  = (float*)alloc((size_t)N_NODES * 64 * 4);
    float* deg  = (float*)alloc((size_t)N_NODES * 4);

    hipMemsetAsync(deg, 0, (size_t)N_NODES * 4, stream);

    k2_transpose_kernel<<<(1024 * 1024) / 256, 256, 0, stream>>>(k2w, k2T);
    k3_permT_kernel<<<(4096 * 1024) / 256, 256, 0, stream>>>(k3w, k3pT);
    b3_permute_kernel<<<16, 256, 0, stream>>>(k3b, b3p);
    deg_kernel<<<(N_EDGES + 255) / 256, 256, 0, stream>>>(ei, deg);

    // h2 = relu(relu(ea@k1+b1)@k2+b2), bf16, once (edge_attr depth-invariant)
    for (int e0 = 0; e0 < N_EDGES; e0 += E_CHUNK) {
        gemm1_kernel<<<(E_CHUNK * 1024) / 256, 256, 0, stream>>>(ea, k1w, k1b, h1ch, e0);
        dim3 g2(1024 / 128, (E_CHUNK + 127) / 128);
        gemm128_kernel<1024, true><<<g2, 256, 0, stream>>>(
            h1ch, k2T, k2b, h2 + (size_t)e0 * 1024, E_CHUNK);
    }

    z0_kernel<<<(N_NODES * 64) / 256, 256, 0, stream>>>(x, fc1w, fc1b, zA);

    float* zin = zA;
    float* zout = zB;
    for (int d = 0; d < DEPTH; d++) {
        hipMemsetAsync(agg, 0, (size_t)N_NODES * 64 * 4, stream);
        dim3 g3(4096 / 256, (N_EDGES + 127) / 128);  // 16 n-blocks x 782 m-blocks
        gemm_msg_kernel<<<g3, 256, 0, stream>>>(h2, k3pT, b3p, ei, zin, agg, N_EDGES);
        update_kernel<<<N_NODES / 4, 256, 0, stream>>>(zin, agg, deg, rootw, convb, zout);
        float* tmp = zin; zin = zout; zout = tmp;
    }

    final_kernel<<<(N_NODES + 255) / 256, 256, 0, stream>>>(zin, fc2w, fc2b, out);
}